// Round 21
// baseline (123.065 us; speedup 1.0000x reference)
//
#include <hip/hip_runtime.h>
#include <hip/hip_bf16.h>
#include <stdint.h>

#define SEQ    2048
#define HIDDEN 1024
#define NH     16
#define HD     64

// log2(e)/8 : folds both the 1/sqrt(64) scale and the exp->exp2 conversion
#define SC_LOG2E_8 0.18033688011112042f
// static softmax shift (log2 domain): exp2(score - 16), normalized by l at the end
#define SM_SHIFT   16.0f

typedef __bf16 bf16x8 __attribute__((ext_vector_type(8)));
typedef float  f32x4  __attribute__((ext_vector_type(4)));
typedef float  f32x16 __attribute__((ext_vector_type(16)));
typedef unsigned int uint32x2 __attribute__((ext_vector_type(2)));

typedef __attribute__((address_space(1))) void* as1vp;
typedef __attribute__((address_space(3))) void* as3vp;

__device__ __forceinline__ void gload_lds16(const void* g, void* l) {
  __builtin_amdgcn_global_load_lds((as1vp)(void*)g, (as3vp)l, 16, 0, 0);
}

__device__ __forceinline__ uint16_t f2bf(float f) {
  uint32_t x;
  __builtin_memcpy(&x, &f, 4);
  x += 0x7FFFu + ((x >> 16) & 1u);   // round-to-nearest-even
  return (uint16_t)(x >> 16);
}

// pack two floats to one u32 of 2 bf16 (lo, hi)
__device__ __forceinline__ uint32_t pkbf(float lo, float hi) {
  union { __bf16 v[2]; uint32_t u; } t;
  t.v[0] = (__bf16)lo; t.v[1] = (__bf16)hi;
  return t.u;
}

// v_permlane32_swap_b32 (builtin): swaps vdst[32:63] <-> vsrc[0:31].
__device__ __forceinline__ uint32x2 plswap(uint32_t lo, uint32_t hi) {
  return __builtin_amdgcn_permlane32_swap(lo, hi, false, false);
}

// value held by partner lane (lane ^ 32)
__device__ __forceinline__ float xhalf32(float x, int lane) {
  uint32_t a;
  __builtin_memcpy(&a, &x, 4);
  uint32x2 r = plswap(a, a);
  uint32_t p = (lane < 32) ? r[1] : r[0];
  float f;
  __builtin_memcpy(&f, &p, 4);
  return f;
}

__device__ __forceinline__ float exp2_fast(float x) {
  return __builtin_amdgcn_exp2f(x);
}

// ---------------------------------------------------------------------------
// Prep kernel (cvt removed -- fused into the GEMM A-path):
//  x < 256 : transpose W fp32 [K][N] -> WT bf16 [N][K] (matrix by y)
//  x == 256, y<2 : mask_sc = mask * log2e/8 - SM_SHIFT
// ---------------------------------------------------------------------------
__global__ __launch_bounds__(256) void k_prep(
    const float* __restrict__ mask,
    const float* __restrict__ W0, const float* __restrict__ W1, const float* __restrict__ W2,
    float* __restrict__ mask_sc,
    uint16_t* __restrict__ T0, uint16_t* __restrict__ T1, uint16_t* __restrict__ T2) {
  __shared__ uint16_t t[64][65];
  if (blockIdx.x == 256) {             // ---- mask path (2 x 256 x 8 = 4096)
    if (blockIdx.y < 2) {
      const int i = (blockIdx.y * 256 + threadIdx.x) * 8;
      float4 a = *(const float4*)(mask + i);
      float4 b = *(const float4*)(mask + i + 4);
      a.x = a.x * SC_LOG2E_8 - SM_SHIFT; a.y = a.y * SC_LOG2E_8 - SM_SHIFT;
      a.z = a.z * SC_LOG2E_8 - SM_SHIFT; a.w = a.w * SC_LOG2E_8 - SM_SHIFT;
      b.x = b.x * SC_LOG2E_8 - SM_SHIFT; b.y = b.y * SC_LOG2E_8 - SM_SHIFT;
      b.z = b.z * SC_LOG2E_8 - SM_SHIFT; b.w = b.w * SC_LOG2E_8 - SM_SHIFT;
      *(float4*)(mask_sc + i) = a;
      *(float4*)(mask_sc + i + 4) = b;
    }
    return;
  }
  const int bi = blockIdx.x;           // ---- transpose path (256 blocks / matrix)
  const float* W = (blockIdx.y == 0) ? W0 : (blockIdx.y == 1) ? W1 : W2;
  uint16_t*    T = (blockIdx.y == 0) ? T0 : (blockIdx.y == 1) ? T1 : T2;
  const int bx = bi & 15, by = bi >> 4;
  const int tx = threadIdx.x & 63, ty = threadIdx.x >> 6;
  for (int i = ty; i < 64; i += 4)
    t[i][tx] = f2bf(W[(by * 64 + i) * HIDDEN + bx * 64 + tx]);
  __syncthreads();
  for (int i = ty; i < 64; i += 4)
    T[(bx * 64 + i) * HIDDEN + by * 64 + tx] = t[tx][i];
}

// ---------------------------------------------------------------------------
// QKV projection GEMM with FUSED fp32->bf16 on the A path, done right:
//  - A staged as fp32 via global_load_lds (no registers; r18's reg-staging
//    serialized at 60 VGPR) into a 32 KB LDS tile with 16B XOR swizzle
//    (r11's unswizzled 256B rows were a 16-way conflict). Source col is
//    pre-swizzled c ^ ((row&7)<<4) (involution); reads XOR the same.
//  - Fragments: 2x ds_read_b128 (f32x8) + 4x cvt_pk -> bf16x8 (fills idle
//    VALU slots; MfmaUtil is only ~35%).
//  - B = WT bf16, unchanged swizzled path. 128x64 tile, BK=64, 4 waves.
//  Grid 1536, bijective XCD swizzle. Fragment-major epilogue (unchanged):
//   q: [bh][qt32(64)][slot(4)][lane(64)][j(8)]  (scaled by log2e/8)
//   k: [bh][kt(32)][c(2)][slot(4)][lane(64)][j(8)]
//   v: [bh][kt(32)][dt(2)][ks(4)][lane(64)][jj(8)]
// ---------------------------------------------------------------------------
__global__ __launch_bounds__(256) void k_qkv_gemm(
    const float* __restrict__ Qf, const float* __restrict__ Kf, const float* __restrict__ Vf,
    const uint16_t* __restrict__ WTq, const uint16_t* __restrict__ WTk, const uint16_t* __restrict__ WTv,
    const float* __restrict__ Bq, const float* __restrict__ Bk, const float* __restrict__ Bv,
    uint16_t* __restrict__ q_ws, uint16_t* __restrict__ k_ws, uint16_t* __restrict__ v_ws) {
  // XCD swizzle: 1536 = 8 x 192; XCD c gets consecutive work-ids 192c..192c+191
  const int wg  = blockIdx.x;
  const int swz = (wg & 7) * 192 + (wg >> 3);
  const int mode = swz >> 9;           // 512 blocks per mode
  const int rem  = swz & 511;
  const int m0   = (rem >> 4) * 128;   // 32 m-tiles
  const int n0   = (rem & 15) * 64;    // 16 n-tiles

  const float*    X   = (mode == 0) ? Qf : (mode == 1) ? Kf : Vf;
  const uint16_t* WT  = (mode == 0) ? WTq : (mode == 1) ? WTk : WTv;
  const float*    bia = (mode == 0) ? Bq  : (mode == 1) ? Bk  : Bv;

  __shared__ float    Asf[128 * 64];   // 32 KB fp32, rows 256B, 16B-XOR swizzled
  __shared__ uint16_t Bs[64 * 64];     // 8 KB bf16, rows 128B, swizzled
  char* AsB = (char*)Asf;
  char* BsB = (char*)Bs;

  const int tid  = threadIdx.x;
  const int lane = tid & 63;
  const int w    = tid >> 6;
  const int wr   = w >> 1, wc = w & 1;  // wave covers rows wr*64.., cols wc*32..

  // B staging geometry (8 rows of 128B per instr)
  const int b_lrow   = lane >> 3;
  const int b_srccol = ((lane & 7) * 16) ^ (b_lrow << 4);
  // A staging geometry (4 rows of 256B per instr)
  const int a_rg     = lane >> 4;        // row within 4-row group

  f32x4 acc[4][2];
  const f32x4 zero = {0.f, 0.f, 0.f, 0.f};
#pragma unroll
  for (int i = 0; i < 4; ++i)
#pragma unroll
    for (int j = 0; j < 2; ++j) acc[i][j] = zero;

  const char* Ab = (const char*)X;     // fp32, row stride 4096 B
  const char* Bb = (const char*)WT;    // bf16, row stride 2048 B

  for (int kt = 0; kt < 16; ++kt) {
    __syncthreads();
    // ---- B: async global->LDS, swizzled source ----
#pragma unroll
    for (int i = 0; i < 2; ++i) {
      const int r = w * 16 + i * 8;
      gload_lds16(Bb + (size_t)(n0 + r + b_lrow) * 2048 + kt * 128 + b_srccol, BsB + r * 128);
    }
    // ---- A: async global->LDS fp32, swizzled source (8 instr/wave) ----
#pragma unroll
    for (int i = 0; i < 8; ++i) {
      const int rb = w * 32 + i * 4;         // multiple of 4
      const int r  = rb + a_rg;
      const int sc = ((lane & 15) * 16) ^ ((r & 7) << 4);
      gload_lds16(Ab + (size_t)(m0 + r) * 4096 + kt * 256 + sc, AsB + rb * 256);
    }
    __syncthreads();
#pragma unroll
    for (int kc = 0; kc < 2; ++kc) {
      const int off32 = kc * 128 + (lane >> 4) * 32;   // fp32 byte offset of 8-elem run
      const int swa   = (lane & 7) << 4;               // = (ra&7)<<4 for all f
      bf16x8 a[4], b[2];
#pragma unroll
      for (int f = 0; f < 4; ++f) {
        const int ra = wr * 64 + f * 16 + (lane & 15);
        const char* ap = AsB + ra * 256;
        f32x4 lo = *(const f32x4*)(ap + (off32 ^ swa));
        f32x4 hi = *(const f32x4*)(ap + ((off32 + 16) ^ swa));
        uint32_t wv[4] = {pkbf(lo[0], lo[1]), pkbf(lo[2], lo[3]),
                          pkbf(hi[0], hi[1]), pkbf(hi[2], hi[3])};
        __builtin_memcpy(&a[f], wv, 16);
      }
      const int chunk = kc * 64 + (lane >> 4) * 16;
#pragma unroll
      for (int f = 0; f < 2; ++f) {
        const int rb = wc * 32 + f * 16 + (lane & 15);
        b[f] = *(const bf16x8*)(BsB + rb * 128 + (chunk ^ ((rb & 7) << 4)));
      }
#pragma unroll
      for (int fm = 0; fm < 4; ++fm)
#pragma unroll
        for (int fn = 0; fn < 2; ++fn)
          acc[fm][fn] = __builtin_amdgcn_mfma_f32_16x16x32_bf16(a[fm], b[fn], acc[fm][fn], 0, 0, 0);
    }
  }

  float bfrag[2];
#pragma unroll
  for (int fn = 0; fn < 2; ++fn)
    bfrag[fn] = bia[n0 + wc * 32 + fn * 16 + (lane & 15)];

#pragma unroll
  for (int fm = 0; fm < 4; ++fm) {
    const int mrow0 = m0 + wr * 64 + fm * 16 + (lane >> 4) * 4;   // run of 4 rows
    const int b0 = mrow0 >> 11;
    const int sq = mrow0 & (SEQ - 1);
#pragma unroll
    for (int fn = 0; fn < 2; ++fn) {
      const int n = n0 + wc * 32 + fn * 16 + (lane & 15);
      const int h = n >> 6, d = n & 63;
      const size_t bh = (size_t)(b0 * NH + h);
      if (mode == 2) {
        const int kt2 = sq >> 6, ks = (sq >> 4) & 3, hv = (sq >> 3) & 1, jj = sq & 7;
        const int dt = d >> 5, lnv = hv * 32 + (d & 31);
        uint16_t tmp[4];
#pragma unroll
        for (int j = 0; j < 4; ++j) tmp[j] = f2bf(acc[fm][fn][j] + bfrag[fn]);
        __builtin_memcpy(v_ws + ((((bh * 32 + kt2) * 2 + dt) * 4 + ks) * 64 + lnv) * 8 + jj,
                         tmp, 8);
      } else if (mode == 1) {
        const int kt2 = sq >> 6, c = (sq >> 5) & 1, ql = sq & 31;
        const int slot = d >> 4, hk = (d >> 3) & 1, jk = d & 7;
        uint16_t* base = k_ws + ((((bh * 32 + kt2) * 2 + c) * 4 + slot) * 64 + hk * 32 + ql) * 8 + jk;
#pragma unroll
        for (int j = 0; j < 4; ++j) base[j * 8] = f2bf(acc[fm][fn][j] + bfrag[fn]);
      } else {
        const int qt32 = sq >> 5, ql = sq & 31;
        const int slot = d >> 4, hq = (d >> 3) & 1, jq = d & 7;
        uint16_t* base = q_ws + (((bh * 64 + qt32) * 4 + slot) * 64 + hq * 32 + ql) * 8 + jq;
#pragma unroll
        for (int j = 0; j < 4; ++j)
          base[j * 8] = f2bf((acc[fm][fn][j] + bfrag[fn]) * SC_LOG2E_8);
      }
    }
  }
}

// ---------------------------------------------------------------------------
// Flash attention (round-19 config, byte-identical -- the 67.2 us plateau):
// swapped-QK^T 32x32, fragment-major operands, static-max softmax, setprio.
// Split-KV x4: block = (bh, 32 q); wave w takes KV quarter (8 tiles).
// Grid 2048, bijective XCD swizzle. Waves 1-3 dump (O,l) to LDS, wave 0 sums.
// ---------------------------------------------------------------------------
__global__ __launch_bounds__(256) void k_attn(
    const uint16_t* __restrict__ q_ws, const uint16_t* __restrict__ k_ws,
    const uint16_t* __restrict__ v_ws, const float* __restrict__ mask_sc,
    float* __restrict__ out) {
  __shared__ float smem[3][64][33];   // partials from waves 1..3: 32 O + l

  const int tid = threadIdx.x, lane = tid & 63, w = tid >> 6;
  const int wg  = blockIdx.x;
  const int swz = (wg & 7) * 256 + (wg >> 3);
  const int bh  = swz >> 6;
  const int qt  = swz & 63;           // 32-q tile index
  const int b   = bh >> 4;
  const int h   = bh & 15;
  const int q0  = qt * 32;
  const int ql  = lane & 31;
  const int hi  = lane >> 5;

  const char* qfb = (const char*)q_ws + ((size_t)bh * 64 + qt) * 4096;
  const char* kfb = (const char*)k_ws + (size_t)bh * 262144 + lane * 16;
  const char* vfb = (const char*)v_ws + (size_t)bh * 262144 + lane * 16;
  const float* mrow = mask_sc + b * SEQ;

  bf16x8 qB[4];
#pragma unroll
  for (int s = 0; s < 4; ++s)
    qB[s] = *(const bf16x8*)(qfb + s * 1024 + lane * 16);

  const f32x16 zero16 = {0.f};
  f32x16 Oacc[2];
  Oacc[0] = zero16; Oacc[1] = zero16;
  float lpart = 0.f;

  const int kbeg = w * 8, kend = kbeg + 8;

  for (int kt = kbeg; kt < kend; ++kt) {
    const char* kt_k = kfb + (size_t)kt * 8192;
    const char* kt_v = vfb + (size_t)kt * 8192;

    bf16x8 kf[8];
#pragma unroll
    for (int i = 0; i < 8; ++i) kf[i] = *(const bf16x8*)(kt_k + i * 1024);

    f32x16 P0, P1;
#pragma unroll
    for (int g = 0; g < 4; ++g) {
      f32x4 mk0 = *(const f32x4*)(mrow + kt * 64 + g * 8 + 4 * hi);
      f32x4 mk1 = *(const f32x4*)(mrow + kt * 64 + 32 + g * 8 + 4 * hi);
#pragma unroll
      for (int t = 0; t < 4; ++t) { P0[g * 4 + t] = mk0[t]; P1[g * 4 + t] = mk1[t]; }
    }

    __builtin_amdgcn_s_setprio(1);
#pragma unroll
    for (int s = 0; s < 4; ++s)
      P0 = __builtin_amdgcn_mfma_f32_32x32x16_bf16(kf[s], qB[s], P0, 0, 0, 0);
#pragma unroll
    for (int s = 0; s < 4; ++s)
      P1 = __builtin_amdgcn_mfma_f32_32x32x16_bf16(kf[4 + s], qB[s], P1, 0, 0, 0);
    __builtin_amdgcn_s_setprio(0);

    bf16x8 vA[8];
#pragma unroll
    for (int i = 0; i < 8; ++i) vA[i] = *(const bf16x8*)(kt_v + i * 1024);

    float s0 = 0.f, s1 = 0.f, s2a = 0.f, s3 = 0.f;
#pragma unroll
    for (int r = 0; r < 16; r += 4) {
      P0[r]     = exp2_fast(P0[r]);      s0  += P0[r];
      P0[r + 1] = exp2_fast(P0[r + 1]);  s1  += P0[r + 1];
      P0[r + 2] = exp2_fast(P0[r + 2]);  s2a += P0[r + 2];
      P0[r + 3] = exp2_fast(P0[r + 3]);  s3  += P0[r + 3];
      P1[r]     = exp2_fast(P1[r]);      s0  += P1[r];
      P1[r + 1] = exp2_fast(P1[r + 1]);  s1  += P1[r + 1];
      P1[r + 2] = exp2_fast(P1[r + 2]);  s2a += P1[r + 2];
      P1[r + 3] = exp2_fast(P1[r + 3]);  s3  += P1[r + 3];
    }
    lpart += (s0 + s1) + (s2a + s3);

    bf16x8 pb[4];
#pragma unroll
    for (int ks = 0; ks < 4; ++ks) {
      const int o = (ks & 1) * 8;
      uint32_t w0, w1, w2, w3;
      if (ks < 2) {
        w0 = pkbf(P0[o + 0], P0[o + 1]);
        w1 = pkbf(P0[o + 2], P0[o + 3]);
        w2 = pkbf(P0[o + 4], P0[o + 5]);
        w3 = pkbf(P0[o + 6], P0[o + 7]);
      } else {
        w0 = pkbf(P1[o + 0], P1[o + 1]);
        w1 = pkbf(P1[o + 2], P1[o + 3]);
        w2 = pkbf(P1[o + 4], P1[o + 5]);
        w3 = pkbf(P1[o + 6], P1[o + 7]);
      }
      uint32x2 r02 = plswap(w0, w2);
      uint32x2 r13 = plswap(w1, w3);
      uint32_t wv[4] = {r02[0], r13[0], r02[1], r13[1]};
      __builtin_memcpy(&pb[ks], wv, 16);
    }

    __builtin_amdgcn_s_setprio(1);
#pragma unroll
    for (int ks = 0; ks < 4; ++ks) {
      Oacc[0] = __builtin_amdgcn_mfma_f32_32x32x16_bf16(vA[ks],     pb[ks], Oacc[0], 0, 0, 0);
      Oacc[1] = __builtin_amdgcn_mfma_f32_32x32x16_bf16(vA[4 + ks], pb[ks], Oacc[1], 0, 0, 0);
    }
    __builtin_amdgcn_s_setprio(0);
  }

  if (w > 0) {
    float* s = smem[w - 1][lane];
#pragma unroll
    for (int r = 0; r < 16; ++r) { s[r] = Oacc[0][r]; s[16 + r] = Oacc[1][r]; }
    s[32] = lpart;
  }
  __syncthreads();
  if (w > 0) return;

#pragma unroll
  for (int p = 0; p < 3; ++p) {
    const float* s = smem[p][lane];
#pragma unroll
    for (int r = 0; r < 16; ++r) { Oacc[0][r] += s[r]; Oacc[1][r] += s[16 + r]; }
    lpart += s[32];
  }

  const float ltot = lpart + xhalf32(lpart, lane);
  const float linv = 1.f / ltot;
  float* orow = out + ((size_t)(b * SEQ) + q0 + ql) * HIDDEN + h * HD;
#pragma unroll
  for (int dt = 0; dt < 2; ++dt)
#pragma unroll
    for (int g = 0; g < 4; ++g) {
      f32x4 o;
#pragma unroll
      for (int t = 0; t < 4; ++t) o[t] = Oacc[dt][g * 4 + t] * linv;
      *(f32x4*)(orow + dt * 32 + g * 8 + 4 * hi) = o;
    }
}

// ---------------------------------------------------------------------------
extern "C" void kernel_launch(void* const* d_in, const int* in_sizes, int n_in,
                              void* d_out, int out_size, void* d_ws, size_t ws_size,
                              hipStream_t stream) {
  (void)in_sizes; (void)n_in; (void)out_size; (void)ws_size;
  const float* Q    = (const float*)d_in[0];
  const float* K    = (const float*)d_in[1];
  const float* V    = (const float*)d_in[2];
  const float* mask = (const float*)d_in[3];
  const float* Wq   = (const float*)d_in[4];
  const float* bq   = (const float*)d_in[5];
  const float* Wk   = (const float*)d_in[6];
  const float* bk   = (const float*)d_in[7];
  const float* Wv   = (const float*)d_in[8];
  const float* bv   = (const float*)d_in[9];

  uint16_t* ws   = (uint16_t*)d_ws;
  uint16_t* wt_q = ws;
  uint16_t* wt_k = wt_q + HIDDEN * HIDDEN;
  uint16_t* wt_v = wt_k + HIDDEN * HIDDEN;
  const size_t qkv = (size_t)2 * SEQ * HIDDEN;
  uint16_t* q_ws = wt_v + HIDDEN * HIDDEN;
  uint16_t* k_ws = q_ws + qkv;
  uint16_t* v_ws = k_ws + qkv;
  float* mask_sc = (float*)(v_ws + qkv);       // 4096 floats (16 KB)

  k_prep<<<dim3(257, 3), 256, 0, stream>>>(mask, Wq, Wk, Wv,
                                           mask_sc, wt_q, wt_k, wt_v);
  k_qkv_gemm<<<dim3(1536), 256, 0, stream>>>(
      Q, K, V, wt_q, wt_k, wt_v, bq, bk, bv, q_ws, k_ws, v_ws);
  k_attn<<<dim3(2048), 256, 0, stream>>>(q_ws, k_ws, v_ws, mask_sc,
                                         (float*)d_out);
}

// Round 22
// 111.671 us; speedup vs baseline: 1.1020x; 1.1020x over previous
//
#include <hip/hip_runtime.h>
#include <hip/hip_bf16.h>
#include <stdint.h>

#define SEQ    2048
#define HIDDEN 1024
#define NH     16
#define HD     64

// log2(e)/8 : folds both the 1/sqrt(64) scale and the exp->exp2 conversion
#define SC_LOG2E_8 0.18033688011112042f
// static softmax shift (log2 domain): exp2(score - 16), normalized by l at the end
#define SM_SHIFT   16.0f

typedef __bf16 bf16x8 __attribute__((ext_vector_type(8)));
typedef float  f32x4  __attribute__((ext_vector_type(4)));
typedef float  f32x16 __attribute__((ext_vector_type(16)));
typedef unsigned int uint32x2 __attribute__((ext_vector_type(2)));

typedef __attribute__((address_space(1))) void* as1vp;
typedef __attribute__((address_space(3))) void* as3vp;

__device__ __forceinline__ void gload_lds16(const void* g, void* l) {
  __builtin_amdgcn_global_load_lds((as1vp)(void*)g, (as3vp)l, 16, 0, 0);
}

__device__ __forceinline__ uint16_t f2bf(float f) {
  uint32_t x;
  __builtin_memcpy(&x, &f, 4);
  x += 0x7FFFu + ((x >> 16) & 1u);   // round-to-nearest-even
  return (uint16_t)(x >> 16);
}

// pack two floats to one u32 of 2 bf16 (lo, hi)
__device__ __forceinline__ uint32_t pkbf(float lo, float hi) {
  union { __bf16 v[2]; uint32_t u; } t;
  t.v[0] = (__bf16)lo; t.v[1] = (__bf16)hi;
  return t.u;
}

// v_permlane32_swap_b32 (builtin): swaps vdst[32:63] <-> vsrc[0:31].
__device__ __forceinline__ uint32x2 plswap(uint32_t lo, uint32_t hi) {
  return __builtin_amdgcn_permlane32_swap(lo, hi, false, false);
}

// value held by partner lane (lane ^ 32)
__device__ __forceinline__ float xhalf32(float x, int lane) {
  uint32_t a;
  __builtin_memcpy(&a, &x, 4);
  uint32x2 r = plswap(a, a);
  uint32_t p = (lane < 32) ? r[1] : r[0];
  float f;
  __builtin_memcpy(&f, &p, 4);
  return f;
}

__device__ __forceinline__ float exp2_fast(float x) {
  return __builtin_amdgcn_exp2f(x);
}

// ---------------------------------------------------------------------------
// Merged prep kernel:
//  x <  2048       : Q/K/V fp32 -> bf16 (tensor by blockIdx.y)
//  x == 2048, y<2  : mask_sc = mask * log2e/8 - SM_SHIFT
//  x >  2048       : transpose W fp32 [K][N] -> WT bf16 [N][K] (matrix by y)
// ---------------------------------------------------------------------------
__global__ __launch_bounds__(256) void k_prep(
    const float* __restrict__ Q, const float* __restrict__ K, const float* __restrict__ V,
    const float* __restrict__ mask,
    const float* __restrict__ W0, const float* __restrict__ W1, const float* __restrict__ W2,
    uint16_t* __restrict__ Qb, uint16_t* __restrict__ Kb, uint16_t* __restrict__ Vb,
    float* __restrict__ mask_sc,
    uint16_t* __restrict__ T0, uint16_t* __restrict__ T1, uint16_t* __restrict__ T2) {
  __shared__ uint16_t t[64][65];
  if (blockIdx.x > 2048) {             // ---- transpose path (256 blocks / matrix)
    const int bi = blockIdx.x - 2049;
    const float* W = (blockIdx.y == 0) ? W0 : (blockIdx.y == 1) ? W1 : W2;
    uint16_t*    T = (blockIdx.y == 0) ? T0 : (blockIdx.y == 1) ? T1 : T2;
    const int bx = bi & 15, by = bi >> 4;
    const int tx = threadIdx.x & 63, ty = threadIdx.x >> 6;
    for (int i = ty; i < 64; i += 4)
      t[i][tx] = f2bf(W[(by * 64 + i) * HIDDEN + bx * 64 + tx]);
    __syncthreads();
    for (int i = ty; i < 64; i += 4)
      T[(bx * 64 + i) * HIDDEN + by * 64 + tx] = t[tx][i];
    return;
  }
  if (blockIdx.x == 2048) {            // ---- mask path (2 x 256 x 8 = 4096)
    if (blockIdx.y < 2) {
      const int i = (blockIdx.y * 256 + threadIdx.x) * 8;
      float4 a = *(const float4*)(mask + i);
      float4 b = *(const float4*)(mask + i + 4);
      a.x = a.x * SC_LOG2E_8 - SM_SHIFT; a.y = a.y * SC_LOG2E_8 - SM_SHIFT;
      a.z = a.z * SC_LOG2E_8 - SM_SHIFT; a.w = a.w * SC_LOG2E_8 - SM_SHIFT;
      b.x = b.x * SC_LOG2E_8 - SM_SHIFT; b.y = b.y * SC_LOG2E_8 - SM_SHIFT;
      b.z = b.z * SC_LOG2E_8 - SM_SHIFT; b.w = b.w * SC_LOG2E_8 - SM_SHIFT;
      *(float4*)(mask_sc + i) = a;
      *(float4*)(mask_sc + i + 4) = b;
    }
    return;
  }
  // ---- cvt path
  const float* src = (blockIdx.y == 0) ? Q : (blockIdx.y == 1) ? K : V;
  uint16_t*    dst = (blockIdx.y == 0) ? Qb : (blockIdx.y == 1) ? Kb : Vb;
  const int i = (blockIdx.x * 256 + threadIdx.x) * 8;
  float4 v0 = *(const float4*)(src + i);
  float4 v1 = *(const float4*)(src + i + 4);
  uint16_t tmp[8];
  tmp[0] = f2bf(v0.x); tmp[1] = f2bf(v0.y); tmp[2] = f2bf(v0.z); tmp[3] = f2bf(v0.w);
  tmp[4] = f2bf(v1.x); tmp[5] = f2bf(v1.y); tmp[6] = f2bf(v1.z); tmp[7] = f2bf(v1.w);
  __builtin_memcpy(dst + i, tmp, 16);
}

// ---------------------------------------------------------------------------
// QKV projection GEMM (round-19 config): 128x64 tile, T2 XOR-swizzled LDS
// (source pre-swizzled + read-side XOR, rule #21), grid 1536, bijective XCD
// swizzle. Fragment-major epilogue:
//  q: [bh][qt32(64)][slot(4)][lane(64)][j(8)]  (scaled by log2e/8)
//  k: [bh][kt(32)][c(2)][slot(4)][lane(64)][j(8)]
//  v: [bh][kt(32)][dt(2)][ks(4)][lane(64)][jj(8)]
// ---------------------------------------------------------------------------
__global__ __launch_bounds__(256) void k_qkv_gemm(
    const uint16_t* __restrict__ Qb, const uint16_t* __restrict__ Kb, const uint16_t* __restrict__ Vb,
    const uint16_t* __restrict__ WTq, const uint16_t* __restrict__ WTk, const uint16_t* __restrict__ WTv,
    const float* __restrict__ Bq, const float* __restrict__ Bk, const float* __restrict__ Bv,
    uint16_t* __restrict__ q_ws, uint16_t* __restrict__ k_ws, uint16_t* __restrict__ v_ws) {
  // XCD swizzle: 1536 = 8 x 192; XCD c gets consecutive work-ids 192c..192c+191
  const int wg  = blockIdx.x;
  const int swz = (wg & 7) * 192 + (wg >> 3);
  const int mode = swz >> 9;           // 512 blocks per mode
  const int rem  = swz & 511;
  const int m0   = (rem >> 4) * 128;   // 32 m-tiles
  const int n0   = (rem & 15) * 64;    // 16 n-tiles

  const uint16_t* X   = (mode == 0) ? Qb : (mode == 1) ? Kb : Vb;
  const uint16_t* WT  = (mode == 0) ? WTq : (mode == 1) ? WTk : WTv;
  const float*    bia = (mode == 0) ? Bq  : (mode == 1) ? Bk  : Bv;

  __shared__ uint16_t As[128 * 64];    // 16 KB
  __shared__ uint16_t Bs[64 * 64];     // 8 KB
  char* AsB = (char*)As;
  char* BsB = (char*)Bs;

  const int tid  = threadIdx.x;
  const int lane = tid & 63;
  const int w    = tid >> 6;
  const int wr   = w >> 1, wc = w & 1;  // wave covers rows wr*64.., cols wc*32..

  const int lrow   = lane >> 3;
  const int srccol = ((lane & 7) * 16) ^ (lrow << 4);   // pre-swizzled source col

  f32x4 acc[4][2];
  const f32x4 zero = {0.f, 0.f, 0.f, 0.f};
#pragma unroll
  for (int i = 0; i < 4; ++i)
#pragma unroll
    for (int j = 0; j < 2; ++j) acc[i][j] = zero;

  const char* Ab = (const char*)X;
  const char* Bb = (const char*)WT;

  for (int kt = 0; kt < 16; ++kt) {
    __syncthreads();
    const int kbyte = kt * 128;
#pragma unroll
    for (int i = 0; i < 4; ++i) {      // A: 128 rows, 32/wave
      const int r = w * 32 + i * 8;
      gload_lds16(Ab + (size_t)(m0 + r + lrow) * (HIDDEN * 2) + kbyte + srccol, AsB + r * 128);
    }
#pragma unroll
    for (int i = 0; i < 2; ++i) {      // B: 64 rows, 16/wave
      const int r = w * 16 + i * 8;
      gload_lds16(Bb + (size_t)(n0 + r + lrow) * (HIDDEN * 2) + kbyte + srccol, BsB + r * 128);
    }
    __syncthreads();
#pragma unroll
    for (int kc = 0; kc < 2; ++kc) {
      const int chunk = kc * 64 + (lane >> 4) * 16;
      bf16x8 a[4], b[2];
#pragma unroll
      for (int f = 0; f < 4; ++f) {
        const int ra = wr * 64 + f * 16 + (lane & 15);
        a[f] = *(const bf16x8*)(AsB + ra * 128 + (chunk ^ ((ra & 7) << 4)));
      }
#pragma unroll
      for (int f = 0; f < 2; ++f) {
        const int rb = wc * 32 + f * 16 + (lane & 15);
        b[f] = *(const bf16x8*)(BsB + rb * 128 + (chunk ^ ((rb & 7) << 4)));
      }
#pragma unroll
      for (int fm = 0; fm < 4; ++fm)
#pragma unroll
        for (int fn = 0; fn < 2; ++fn)
          acc[fm][fn] = __builtin_amdgcn_mfma_f32_16x16x32_bf16(a[fm], b[fn], acc[fm][fn], 0, 0, 0);
    }
  }

  float bfrag[2];
#pragma unroll
  for (int fn = 0; fn < 2; ++fn)
    bfrag[fn] = bia[n0 + wc * 32 + fn * 16 + (lane & 15)];

#pragma unroll
  for (int fm = 0; fm < 4; ++fm) {
    const int mrow0 = m0 + wr * 64 + fm * 16 + (lane >> 4) * 4;   // run of 4 rows
    const int b0 = mrow0 >> 11;
    const int sq = mrow0 & (SEQ - 1);
#pragma unroll
    for (int fn = 0; fn < 2; ++fn) {
      const int n = n0 + wc * 32 + fn * 16 + (lane & 15);
      const int h = n >> 6, d = n & 63;
      const size_t bh = (size_t)(b0 * NH + h);
      if (mode == 2) {
        const int kt2 = sq >> 6, ks = (sq >> 4) & 3, hv = (sq >> 3) & 1, jj = sq & 7;
        const int dt = d >> 5, lnv = hv * 32 + (d & 31);
        uint16_t tmp[4];
#pragma unroll
        for (int j = 0; j < 4; ++j) tmp[j] = f2bf(acc[fm][fn][j] + bfrag[fn]);
        __builtin_memcpy(v_ws + ((((bh * 32 + kt2) * 2 + dt) * 4 + ks) * 64 + lnv) * 8 + jj,
                         tmp, 8);
      } else if (mode == 1) {
        const int kt2 = sq >> 6, c = (sq >> 5) & 1, ql = sq & 31;
        const int slot = d >> 4, hk = (d >> 3) & 1, jk = d & 7;
        uint16_t* base = k_ws + ((((bh * 32 + kt2) * 2 + c) * 4 + slot) * 64 + hk * 32 + ql) * 8 + jk;
#pragma unroll
        for (int j = 0; j < 4; ++j) base[j * 8] = f2bf(acc[fm][fn][j] + bfrag[fn]);
      } else {
        const int qt32 = sq >> 5, ql = sq & 31;
        const int slot = d >> 4, hq = (d >> 3) & 1, jq = d & 7;
        uint16_t* base = q_ws + (((bh * 64 + qt32) * 4 + slot) * 64 + hq * 32 + ql) * 8 + jq;
#pragma unroll
        for (int j = 0; j < 4; ++j)
          base[j * 8] = f2bf((acc[fm][fn][j] + bfrag[fn]) * SC_LOG2E_8);
      }
    }
  }
}

// ---------------------------------------------------------------------------
// Flash attention (round-19 config, the 67.2 us plateau): swapped-QK^T 32x32,
// fragment-major operands, static-max softmax, setprio. Split-KV x4:
// block = (bh, 32 q); wave w takes KV quarter (8 tiles). Grid 2048,
// bijective XCD swizzle. Waves 1-3 dump (O,l) to LDS, wave 0 sums.
// ---------------------------------------------------------------------------
__global__ __launch_bounds__(256) void k_attn(
    const uint16_t* __restrict__ q_ws, const uint16_t* __restrict__ k_ws,
    const uint16_t* __restrict__ v_ws, const float* __restrict__ mask_sc,
    float* __restrict__ out) {
  __shared__ float smem[3][64][33];   // partials from waves 1..3: 32 O + l

  const int tid = threadIdx.x, lane = tid & 63, w = tid >> 6;
  const int wg  = blockIdx.x;
  const int swz = (wg & 7) * 256 + (wg >> 3);
  const int bh  = swz >> 6;
  const int qt  = swz & 63;           // 32-q tile index
  const int b   = bh >> 4;
  const int h   = bh & 15;
  const int q0  = qt * 32;
  const int ql  = lane & 31;
  const int hi  = lane >> 5;

  const char* qfb = (const char*)q_ws + ((size_t)bh * 64 + qt) * 4096;
  const char* kfb = (const char*)k_ws + (size_t)bh * 262144 + lane * 16;
  const char* vfb = (const char*)v_ws + (size_t)bh * 262144 + lane * 16;
  const float* mrow = mask_sc + b * SEQ;

  bf16x8 qB[4];
#pragma unroll
  for (int s = 0; s < 4; ++s)
    qB[s] = *(const bf16x8*)(qfb + s * 1024 + lane * 16);

  const f32x16 zero16 = {0.f};
  f32x16 Oacc[2];
  Oacc[0] = zero16; Oacc[1] = zero16;
  float lpart = 0.f;

  const int kbeg = w * 8, kend = kbeg + 8;

  for (int kt = kbeg; kt < kend; ++kt) {
    const char* kt_k = kfb + (size_t)kt * 8192;
    const char* kt_v = vfb + (size_t)kt * 8192;

    bf16x8 kf[8];
#pragma unroll
    for (int i = 0; i < 8; ++i) kf[i] = *(const bf16x8*)(kt_k + i * 1024);

    f32x16 P0, P1;
#pragma unroll
    for (int g = 0; g < 4; ++g) {
      f32x4 mk0 = *(const f32x4*)(mrow + kt * 64 + g * 8 + 4 * hi);
      f32x4 mk1 = *(const f32x4*)(mrow + kt * 64 + 32 + g * 8 + 4 * hi);
#pragma unroll
      for (int t = 0; t < 4; ++t) { P0[g * 4 + t] = mk0[t]; P1[g * 4 + t] = mk1[t]; }
    }

    __builtin_amdgcn_s_setprio(1);
#pragma unroll
    for (int s = 0; s < 4; ++s)
      P0 = __builtin_amdgcn_mfma_f32_32x32x16_bf16(kf[s], qB[s], P0, 0, 0, 0);
#pragma unroll
    for (int s = 0; s < 4; ++s)
      P1 = __builtin_amdgcn_mfma_f32_32x32x16_bf16(kf[4 + s], qB[s], P1, 0, 0, 0);
    __builtin_amdgcn_s_setprio(0);

    bf16x8 vA[8];
#pragma unroll
    for (int i = 0; i < 8; ++i) vA[i] = *(const bf16x8*)(kt_v + i * 1024);

    float s0 = 0.f, s1 = 0.f, s2a = 0.f, s3 = 0.f;
#pragma unroll
    for (int r = 0; r < 16; r += 4) {
      P0[r]     = exp2_fast(P0[r]);      s0  += P0[r];
      P0[r + 1] = exp2_fast(P0[r + 1]);  s1  += P0[r + 1];
      P0[r + 2] = exp2_fast(P0[r + 2]);  s2a += P0[r + 2];
      P0[r + 3] = exp2_fast(P0[r + 3]);  s3  += P0[r + 3];
      P1[r]     = exp2_fast(P1[r]);      s0  += P1[r];
      P1[r + 1] = exp2_fast(P1[r + 1]);  s1  += P1[r + 1];
      P1[r + 2] = exp2_fast(P1[r + 2]);  s2a += P1[r + 2];
      P1[r + 3] = exp2_fast(P1[r + 3]);  s3  += P1[r + 3];
    }
    lpart += (s0 + s1) + (s2a + s3);

    bf16x8 pb[4];
#pragma unroll
    for (int ks = 0; ks < 4; ++ks) {
      const int o = (ks & 1) * 8;
      uint32_t w0, w1, w2, w3;
      if (ks < 2) {
        w0 = pkbf(P0[o + 0], P0[o + 1]);
        w1 = pkbf(P0[o + 2], P0[o + 3]);
        w2 = pkbf(P0[o + 4], P0[o + 5]);
        w3 = pkbf(P0[o + 6], P0[o + 7]);
      } else {
        w0 = pkbf(P1[o + 0], P1[o + 1]);
        w1 = pkbf(P1[o + 2], P1[o + 3]);
        w2 = pkbf(P1[o + 4], P1[o + 5]);
        w3 = pkbf(P1[o + 6], P1[o + 7]);
      }
      uint32x2 r02 = plswap(w0, w2);
      uint32x2 r13 = plswap(w1, w3);
      uint32_t wv[4] = {r02[0], r13[0], r02[1], r13[1]};
      __builtin_memcpy(&pb[ks], wv, 16);
    }

    __builtin_amdgcn_s_setprio(1);
#pragma unroll
    for (int ks = 0; ks < 4; ++ks) {
      Oacc[0] = __builtin_amdgcn_mfma_f32_32x32x16_bf16(vA[ks],     pb[ks], Oacc[0], 0, 0, 0);
      Oacc[1] = __builtin_amdgcn_mfma_f32_32x32x16_bf16(vA[4 + ks], pb[ks], Oacc[1], 0, 0, 0);
    }
    __builtin_amdgcn_s_setprio(0);
  }

  if (w > 0) {
    float* s = smem[w - 1][lane];
#pragma unroll
    for (int r = 0; r < 16; ++r) { s[r] = Oacc[0][r]; s[16 + r] = Oacc[1][r]; }
    s[32] = lpart;
  }
  __syncthreads();
  if (w > 0) return;

#pragma unroll
  for (int p = 0; p < 3; ++p) {
    const float* s = smem[p][lane];
#pragma unroll
    for (int r = 0; r < 16; ++r) { Oacc[0][r] += s[r]; Oacc[1][r] += s[16 + r]; }
    lpart += s[32];
  }

  const float ltot = lpart + xhalf32(lpart, lane);
  const float linv = 1.f / ltot;
  float* orow = out + ((size_t)(b * SEQ) + q0 + ql) * HIDDEN + h * HD;
#pragma unroll
  for (int dt = 0; dt < 2; ++dt)
#pragma unroll
    for (int g = 0; g < 4; ++g) {
      f32x4 o;
#pragma unroll
      for (int t = 0; t < 4; ++t) o[t] = Oacc[dt][g * 4 + t] * linv;
      *(f32x4*)(orow + dt * 32 + g * 8 + 4 * hi) = o;
    }
}

// ---------------------------------------------------------------------------
extern "C" void kernel_launch(void* const* d_in, const int* in_sizes, int n_in,
                              void* d_out, int out_size, void* d_ws, size_t ws_size,
                              hipStream_t stream) {
  (void)in_sizes; (void)n_in; (void)out_size; (void)ws_size;
  const float* Q    = (const float*)d_in[0];
  const float* K    = (const float*)d_in[1];
  const float* V    = (const float*)d_in[2];
  const float* mask = (const float*)d_in[3];
  const float* Wq   = (const float*)d_in[4];
  const float* bq   = (const float*)d_in[5];
  const float* Wk   = (const float*)d_in[6];
  const float* bk   = (const float*)d_in[7];
  const float* Wv   = (const float*)d_in[8];
  const float* bv   = (const float*)d_in[9];

  uint16_t* ws   = (uint16_t*)d_ws;
  uint16_t* wt_q = ws;
  uint16_t* wt_k = wt_q + HIDDEN * HIDDEN;
  uint16_t* wt_v = wt_k + HIDDEN * HIDDEN;
  const size_t qkv = (size_t)2 * SEQ * HIDDEN;
  uint16_t* Qb   = wt_v + HIDDEN * HIDDEN;
  uint16_t* Kb   = Qb + qkv;
  uint16_t* Vb   = Kb + qkv;
  uint16_t* q_ws = Vb + qkv;
  uint16_t* k_ws = q_ws + qkv;
  uint16_t* v_ws = k_ws + qkv;
  float* mask_sc = (float*)(v_ws + qkv);       // 4096 floats (16 KB)

  k_prep<<<dim3(2305, 3), 256, 0, stream>>>(Q, K, V, mask, Wq, Wk, Wv,
                                            Qb, Kb, Vb, mask_sc,
                                            wt_q, wt_k, wt_v);
  k_qkv_gemm<<<dim3(1536), 256, 0, stream>>>(
      Qb, Kb, Vb, wt_q, wt_k, wt_v, bq, bk, bv, q_ws, k_ws, v_ws);
  k_attn<<<dim3(2048), 256, 0, stream>>>(q_ws, k_ws, v_ws, mask_sc,
                                         (float*)d_out);
}